// Round 2
// baseline (359.434 us; speedup 1.0000x reference)
//
#include <hip/hip_runtime.h>

#define IMG_H 1024
#define IMG_W 1024
#define RPB   16      // output rows per block
#define TPB   256     // threads per block; each thread owns 4 columns

struct HS { float x[4], y[4], xx[4], yy[4], xy[4]; };

__device__ __forceinline__ void zero_hs(HS& h)
{
#pragma unroll
    for (int j = 0; j < 4; ++j) { h.x[j]=0.f; h.y[j]=0.f; h.xx[j]=0.f; h.yy[j]=0.f; h.xy[j]=0.f; }
}

__device__ __forceinline__ void load_hs(const float* __restrict__ xr,
                                        const float* __restrict__ yr,
                                        int c, HS& h)
{
    float4 xv = *reinterpret_cast<const float4*>(xr + c);
    float4 yv = *reinterpret_cast<const float4*>(yr + c);
    float xs[6], ys[6];
    xs[0] = (c > 0) ? xr[c - 1] : 0.0f;
    ys[0] = (c > 0) ? yr[c - 1] : 0.0f;
    xs[1] = xv.x; xs[2] = xv.y; xs[3] = xv.z; xs[4] = xv.w;
    ys[1] = yv.x; ys[2] = yv.y; ys[3] = yv.z; ys[4] = yv.w;
    xs[5] = (c + 4 < IMG_W) ? xr[c + 4] : 0.0f;
    ys[5] = (c + 4 < IMG_W) ? yr[c + 4] : 0.0f;

    float pxx[6], pyy[6], pxy[6];
#pragma unroll
    for (int k = 0; k < 6; ++k) {
        pxx[k] = xs[k] * xs[k];
        pyy[k] = ys[k] * ys[k];
        pxy[k] = xs[k] * ys[k];
    }
#pragma unroll
    for (int j = 0; j < 4; ++j) {
        h.x[j]  = xs[j]  + xs[j + 1]  + xs[j + 2];
        h.y[j]  = ys[j]  + ys[j + 1]  + ys[j + 2];
        h.xx[j] = pxx[j] + pxx[j + 1] + pxx[j + 2];
        h.yy[j] = pyy[j] + pyy[j + 1] + pyy[j + 2];
        h.xy[j] = pxy[j] + pxy[j + 1] + pxy[j + 2];
    }
}

// Scaled SSIM: multiply both factors of num and den by 81.
//   num = (2*sx*sy + 81*C1) * (18*sxy - 2*sx*sy + 81*C2)
//   den = (sx^2+sy^2 + 81*C1) * (9*(sxx+syy) - (sx^2+sy^2) + 81*C2) + 6561*EPS
__device__ __forceinline__ void accum(const HS& A, const HS& B, const HS& C, float& acc)
{
    const float c1s  = 81.0f * 1e-4f;    // 81*C1
    const float c2s  = 81.0f * 9e-4f;    // 81*C2
    const float epss = 6561.0f * 1e-8f;  // 6561*EPS
#pragma unroll
    for (int j = 0; j < 4; ++j) {
        const float sx  = A.x[j]  + B.x[j]  + C.x[j];
        const float sy  = A.y[j]  + B.y[j]  + C.y[j];
        const float sxx = A.xx[j] + B.xx[j] + C.xx[j];
        const float syy = A.yy[j] + B.yy[j] + C.yy[j];
        const float sxy = A.xy[j] + B.xy[j] + C.xy[j];

        const float t1 = sx * sy;
        const float t2 = fmaf(sx, sx, sy * sy);
        const float s2 = sxx + syy;
        const float An = fmaf(2.0f, t1, c1s);
        const float Bn = fmaf(-2.0f, t1, fmaf(18.0f, sxy, c2s));
        const float Xd = t2 + c1s;
        const float Yd = fmaf(9.0f, s2, c2s - t2);
        const float den = fmaf(Xd, Yd, epss);
        const float num = An * Bn;
        acc = fmaf(num, __builtin_amdgcn_rcpf(den), acc);
    }
}

__global__ __launch_bounds__(TPB)
void ssim_map_sum_kernel(const float* __restrict__ x,
                         const float* __restrict__ y,
                         float* __restrict__ ws_sum)
{
    const int rb = blockIdx.x;
    const int n  = blockIdx.y;
    const int r0 = rb * RPB;
    const int c  = (int)threadIdx.x * 4;

    const float* xi = x + (size_t)n * IMG_H * IMG_W;
    const float* yi = y + (size_t)n * IMG_H * IMG_W;

    HS hA, hB, hC;
    if (r0 > 0) load_hs(xi + (size_t)(r0 - 1) * IMG_W, yi + (size_t)(r0 - 1) * IMG_W, c, hA);
    else        zero_hs(hA);
    load_hs(xi + (size_t)r0 * IMG_W, yi + (size_t)r0 * IMG_W, c, hB);

    float acc = 0.0f;

    // Fully-unrolled 3-phase rotation: output row r0+k uses (P=row-1, Q=row, R=row+1).
#define STEP(P, Q, R, k)                                                          \
    {                                                                             \
        const int nr = r0 + (k) + 1;                                              \
        if (nr < IMG_H)                                                           \
            load_hs(xi + (size_t)nr * IMG_W, yi + (size_t)nr * IMG_W, c, R);      \
        else                                                                      \
            zero_hs(R);                                                           \
        accum(P, Q, R, acc);                                                      \
    }

    STEP(hA, hB, hC, 0)   STEP(hB, hC, hA, 1)   STEP(hC, hA, hB, 2)
    STEP(hA, hB, hC, 3)   STEP(hB, hC, hA, 4)   STEP(hC, hA, hB, 5)
    STEP(hA, hB, hC, 6)   STEP(hB, hC, hA, 7)   STEP(hC, hA, hB, 8)
    STEP(hA, hB, hC, 9)   STEP(hB, hC, hA, 10)  STEP(hC, hA, hB, 11)
    STEP(hA, hB, hC, 12)  STEP(hB, hC, hA, 13)  STEP(hC, hA, hB, 14)
    STEP(hA, hB, hC, 15)
#undef STEP

    // wave (64-lane) reduction
#pragma unroll
    for (int off = 32; off > 0; off >>= 1)
        acc += __shfl_down(acc, off);

    __shared__ float red[TPB / 64];
    const int lane = (int)threadIdx.x & 63;
    const int wave = (int)threadIdx.x >> 6;
    if (lane == 0) red[wave] = acc;
    __syncthreads();
    if (threadIdx.x == 0) {
        float s = 0.0f;
#pragma unroll
        for (int w = 0; w < TPB / 64; ++w) s += red[w];
        atomicAdd(ws_sum, s);
    }
}

__global__ void ssim_finalize_kernel(const float* __restrict__ ws_sum,
                                     float* __restrict__ out,
                                     float inv_count)
{
    out[0] = 1.0f - ws_sum[0] * inv_count;
}

extern "C" void kernel_launch(void* const* d_in, const int* in_sizes, int n_in,
                              void* d_out, int out_size, void* d_ws, size_t ws_size,
                              hipStream_t stream)
{
    const float* x = (const float*)d_in[0];
    const float* y = (const float*)d_in[1];
    float* out  = (float*)d_out;
    float* wsum = (float*)d_ws;

    const long long total = (long long)in_sizes[0];       // 32*1024*1024
    const int N = (int)(total / ((long long)IMG_H * IMG_W));

    hipMemsetAsync(wsum, 0, sizeof(float), stream);

    dim3 grid(IMG_H / RPB, N);
    ssim_map_sum_kernel<<<grid, TPB, 0, stream>>>(x, y, wsum);

    ssim_finalize_kernel<<<1, 1, 0, stream>>>(wsum, out, 1.0f / (float)total);
}

// Round 3
// 297.509 us; speedup vs baseline: 1.2081x; 1.2081x over previous
//
#include <hip/hip_runtime.h>

#define IMG_H 1024
#define IMG_W 1024
#define RPB   16      // output rows per block
#define TPB   256     // threads per block; each thread owns 4 columns

struct HS { float x[4], y[4], xx[4], yy[4], xy[4]; };

__device__ __forceinline__ void zero_hs(HS& h)
{
#pragma unroll
    for (int j = 0; j < 4; ++j) { h.x[j]=0.f; h.y[j]=0.f; h.xx[j]=0.f; h.yy[j]=0.f; h.xy[j]=0.f; }
}

__device__ __forceinline__ void load_hs(const float* __restrict__ xr,
                                        const float* __restrict__ yr,
                                        int c, HS& h)
{
    float4 xv = *reinterpret_cast<const float4*>(xr + c);
    float4 yv = *reinterpret_cast<const float4*>(yr + c);
    float xs[6], ys[6];
    xs[0] = (c > 0) ? xr[c - 1] : 0.0f;
    ys[0] = (c > 0) ? yr[c - 1] : 0.0f;
    xs[1] = xv.x; xs[2] = xv.y; xs[3] = xv.z; xs[4] = xv.w;
    ys[1] = yv.x; ys[2] = yv.y; ys[3] = yv.z; ys[4] = yv.w;
    xs[5] = (c + 4 < IMG_W) ? xr[c + 4] : 0.0f;
    ys[5] = (c + 4 < IMG_W) ? yr[c + 4] : 0.0f;

    float pxx[6], pyy[6], pxy[6];
#pragma unroll
    for (int k = 0; k < 6; ++k) {
        pxx[k] = xs[k] * xs[k];
        pyy[k] = ys[k] * ys[k];
        pxy[k] = xs[k] * ys[k];
    }
#pragma unroll
    for (int j = 0; j < 4; ++j) {
        h.x[j]  = xs[j]  + xs[j + 1]  + xs[j + 2];
        h.y[j]  = ys[j]  + ys[j + 1]  + ys[j + 2];
        h.xx[j] = pxx[j] + pxx[j + 1] + pxx[j + 2];
        h.yy[j] = pyy[j] + pyy[j + 1] + pyy[j + 2];
        h.xy[j] = pxy[j] + pxy[j + 1] + pxy[j + 2];
    }
}

// Scaled SSIM: multiply both factors of num and den by 81 (fold 1/9 away).
//   num = (2*sx*sy + 81*C1) * (18*sxy - 2*sx*sy + 81*C2)
//   den = (sx^2+sy^2 + 81*C1) * (9*(sxx+syy) - (sx^2+sy^2) + 81*C2) + 6561*EPS
__device__ __forceinline__ void accum(const HS& A, const HS& B, const HS& C, float& acc)
{
    const float c1s  = 81.0f * 1e-4f;    // 81*C1
    const float c2s  = 81.0f * 9e-4f;    // 81*C2
    const float epss = 6561.0f * 1e-8f;  // 6561*EPS
#pragma unroll
    for (int j = 0; j < 4; ++j) {
        const float sx  = A.x[j]  + B.x[j]  + C.x[j];
        const float sy  = A.y[j]  + B.y[j]  + C.y[j];
        const float sxx = A.xx[j] + B.xx[j] + C.xx[j];
        const float syy = A.yy[j] + B.yy[j] + C.yy[j];
        const float sxy = A.xy[j] + B.xy[j] + C.xy[j];

        const float t1 = sx * sy;
        const float t2 = fmaf(sx, sx, sy * sy);
        const float s2 = sxx + syy;
        const float An = fmaf(2.0f, t1, c1s);
        const float Bn = fmaf(-2.0f, t1, fmaf(18.0f, sxy, c2s));
        const float Xd = t2 + c1s;
        const float Yd = fmaf(9.0f, s2, c2s - t2);
        const float den = fmaf(Xd, Yd, epss);
        const float num = An * Bn;
        acc = fmaf(num, __builtin_amdgcn_rcpf(den), acc);
    }
}

__global__ __launch_bounds__(TPB)
void ssim_map_sum_kernel(const float* __restrict__ x,
                         const float* __restrict__ y,
                         float* __restrict__ ws_sum)
{
    const int rb = blockIdx.x;
    const int n  = blockIdx.y;
    const int r0 = rb * RPB;
    const int c  = (int)threadIdx.x * 4;

    const float* xi = x + (size_t)n * IMG_H * IMG_W;
    const float* yi = y + (size_t)n * IMG_H * IMG_W;

    HS hA, hB, hC;
    if (r0 > 0) load_hs(xi + (size_t)(r0 - 1) * IMG_W, yi + (size_t)(r0 - 1) * IMG_W, c, hA);
    else        zero_hs(hA);
    load_hs(xi + (size_t)r0 * IMG_W, yi + (size_t)r0 * IMG_W, c, hB);

    float acc = 0.0f;

    // Rolling 3-row ring (NOT unrolled: keeps VGPR pressure low — R2's full
    // unroll hit 192 VGPRs / 11% occupancy and regressed 117->180 us).
    for (int i = 0; i < RPB; ++i) {
        const int r = r0 + i;
        if (r + 1 < IMG_H) {
            load_hs(xi + (size_t)(r + 1) * IMG_W, yi + (size_t)(r + 1) * IMG_W, c, hC);
        } else {
            zero_hs(hC);
        }

        accum(hA, hB, hC, acc);

        // shift ring: A <- B, B <- C
#pragma unroll
        for (int j = 0; j < 4; ++j) {
            hA.x[j]=hB.x[j]; hA.y[j]=hB.y[j]; hA.xx[j]=hB.xx[j]; hA.yy[j]=hB.yy[j]; hA.xy[j]=hB.xy[j];
            hB.x[j]=hC.x[j]; hB.y[j]=hC.y[j]; hB.xx[j]=hC.xx[j]; hB.yy[j]=hC.yy[j]; hB.xy[j]=hC.xy[j];
        }
    }

    // wave (64-lane) reduction
#pragma unroll
    for (int off = 32; off > 0; off >>= 1)
        acc += __shfl_down(acc, off);

    __shared__ float red[TPB / 64];
    const int lane = (int)threadIdx.x & 63;
    const int wave = (int)threadIdx.x >> 6;
    if (lane == 0) red[wave] = acc;
    __syncthreads();
    if (threadIdx.x == 0) {
        float s = 0.0f;
#pragma unroll
        for (int w = 0; w < TPB / 64; ++w) s += red[w];
        atomicAdd(ws_sum, s);
    }
}

__global__ void ssim_finalize_kernel(const float* __restrict__ ws_sum,
                                     float* __restrict__ out,
                                     float inv_count)
{
    out[0] = 1.0f - ws_sum[0] * inv_count;
}

extern "C" void kernel_launch(void* const* d_in, const int* in_sizes, int n_in,
                              void* d_out, int out_size, void* d_ws, size_t ws_size,
                              hipStream_t stream)
{
    const float* x = (const float*)d_in[0];
    const float* y = (const float*)d_in[1];
    float* out  = (float*)d_out;
    float* wsum = (float*)d_ws;

    const long long total = (long long)in_sizes[0];       // 32*1024*1024
    const int N = (int)(total / ((long long)IMG_H * IMG_W));

    hipMemsetAsync(wsum, 0, sizeof(float), stream);

    dim3 grid(IMG_H / RPB, N);
    ssim_map_sum_kernel<<<grid, TPB, 0, stream>>>(x, y, wsum);

    ssim_finalize_kernel<<<1, 1, 0, stream>>>(wsum, out, 1.0f / (float)total);
}

// Round 4
// 287.697 us; speedup vs baseline: 1.2494x; 1.0341x over previous
//
#include <hip/hip_runtime.h>

#define IMG_H 1024
#define IMG_W 1024
#define RPB   16      // output rows per block (RPB-1 divisible by 3 for the unroll)
#define TPB   256     // threads per block; each thread owns 4 columns

struct HS { float x[4], y[4], xx[4], yy[4], xy[4]; };

__device__ __forceinline__ void zero_hs(HS& h)
{
#pragma unroll
    for (int j = 0; j < 4; ++j) { h.x[j]=0.f; h.y[j]=0.f; h.xx[j]=0.f; h.yy[j]=0.f; h.xy[j]=0.f; }
}

__device__ __forceinline__ void load_hs(const float* __restrict__ xr,
                                        const float* __restrict__ yr,
                                        int c, HS& h)
{
    float4 xv = *reinterpret_cast<const float4*>(xr + c);
    float4 yv = *reinterpret_cast<const float4*>(yr + c);
    float xs[6], ys[6];
    xs[0] = (c > 0) ? xr[c - 1] : 0.0f;
    ys[0] = (c > 0) ? yr[c - 1] : 0.0f;
    xs[1] = xv.x; xs[2] = xv.y; xs[3] = xv.z; xs[4] = xv.w;
    ys[1] = yv.x; ys[2] = yv.y; ys[3] = yv.z; ys[4] = yv.w;
    xs[5] = (c + 4 < IMG_W) ? xr[c + 4] : 0.0f;
    ys[5] = (c + 4 < IMG_W) ? yr[c + 4] : 0.0f;

    float pxx[6], pyy[6], pxy[6];
#pragma unroll
    for (int k = 0; k < 6; ++k) {
        pxx[k] = xs[k] * xs[k];
        pyy[k] = ys[k] * ys[k];
        pxy[k] = xs[k] * ys[k];
    }
#pragma unroll
    for (int j = 0; j < 4; ++j) {
        h.x[j]  = xs[j]  + xs[j + 1]  + xs[j + 2];
        h.y[j]  = ys[j]  + ys[j + 1]  + ys[j + 2];
        h.xx[j] = pxx[j] + pxx[j + 1] + pxx[j + 2];
        h.yy[j] = pyy[j] + pyy[j + 1] + pyy[j + 2];
        h.xy[j] = pxy[j] + pxy[j + 1] + pxy[j + 2];
    }
}

// Scaled SSIM: multiply both factors of num and den by 81 (fold 1/9 away).
//   num = (2*sx*sy + 81*C1) * (18*sxy - 2*sx*sy + 81*C2)
//   den = (sx^2+sy^2 + 81*C1) * (9*(sxx+syy) - (sx^2+sy^2) + 81*C2) + 6561*EPS
__device__ __forceinline__ void accum(const HS& A, const HS& B, const HS& C, float& acc)
{
    const float c1s  = 81.0f * 1e-4f;    // 81*C1
    const float c2s  = 81.0f * 9e-4f;    // 81*C2
    const float epss = 6561.0f * 1e-8f;  // 6561*EPS
#pragma unroll
    for (int j = 0; j < 4; ++j) {
        const float sx  = A.x[j]  + B.x[j]  + C.x[j];
        const float sy  = A.y[j]  + B.y[j]  + C.y[j];
        const float sxx = A.xx[j] + B.xx[j] + C.xx[j];
        const float syy = A.yy[j] + B.yy[j] + C.yy[j];
        const float sxy = A.xy[j] + B.xy[j] + C.xy[j];

        const float t1 = sx * sy;
        const float t2 = fmaf(sx, sx, sy * sy);
        const float s2 = sxx + syy;
        const float An = fmaf(2.0f, t1, c1s);
        const float Bn = fmaf(-2.0f, t1, fmaf(18.0f, sxy, c2s));
        const float Xd = t2 + c1s;
        const float Yd = fmaf(9.0f, s2, c2s - t2);
        const float den = fmaf(Xd, Yd, epss);
        const float num = An * Bn;
        acc = fmaf(num, __builtin_amdgcn_rcpf(den), acc);
    }
}

// min-waves/EU=4 caps VGPR at 128: prevents an R2-style 192-VGPR explosion
// while still letting the compiler hoist loads across the 3-step body.
__global__ __launch_bounds__(TPB, 4)
void ssim_map_sum_kernel(const float* __restrict__ x,
                         const float* __restrict__ y,
                         float* __restrict__ ws_sum)
{
    const int rb = blockIdx.x;
    const int n  = blockIdx.y;
    const int r0 = rb * RPB;
    const int c  = (int)threadIdx.x * 4;

    const float* xi = x + (size_t)n * IMG_H * IMG_W;
    const float* yi = y + (size_t)n * IMG_H * IMG_W;

    HS hA, hB, hC;
    if (r0 > 0) load_hs(xi + (size_t)(r0 - 1) * IMG_W, yi + (size_t)(r0 - 1) * IMG_W, c, hA);
    else        zero_hs(hA);
    load_hs(xi + (size_t)r0 * IMG_W, yi + (size_t)r0 * IMG_W, c, hB);

    float acc = 0.0f;

    // Output row r0+k consumes rows (r0+k-1, r0+k, r0+k+1). For k=0..RPB-2 the
    // loaded row r0+k+1 <= r0+RPB-1 < IMG_H is ALWAYS valid -> branch-free body,
    // unrolled x3 with role rotation (no ring-shift movs, loads hoistable).
#define STEP_U(P, Q, R, k)                                                        \
    load_hs(xi + (size_t)(r0 + (k) + 1) * IMG_W,                                  \
            yi + (size_t)(r0 + (k) + 1) * IMG_W, c, R);                           \
    accum(P, Q, R, acc);

    for (int ii = 0; ii < RPB - 1; ii += 3) {
        STEP_U(hA, hB, hC, ii + 0)
        STEP_U(hB, hC, hA, ii + 1)
        STEP_U(hC, hA, hB, ii + 2)
    }
#undef STEP_U

    // Peeled last output row (r0+RPB-1): needs row r0+RPB, out of range only
    // for the last block-row. Wave-uniform branch.
    if (r0 + RPB < IMG_H)
        load_hs(xi + (size_t)(r0 + RPB) * IMG_W, yi + (size_t)(r0 + RPB) * IMG_W, c, hC);
    else
        zero_hs(hC);
    accum(hA, hB, hC, acc);

    // wave (64-lane) reduction
#pragma unroll
    for (int off = 32; off > 0; off >>= 1)
        acc += __shfl_down(acc, off);

    __shared__ float red[TPB / 64];
    const int lane = (int)threadIdx.x & 63;
    const int wave = (int)threadIdx.x >> 6;
    if (lane == 0) red[wave] = acc;
    __syncthreads();
    if (threadIdx.x == 0) {
        float s = 0.0f;
#pragma unroll
        for (int w = 0; w < TPB / 64; ++w) s += red[w];
        atomicAdd(ws_sum, s);
    }
}

__global__ void ssim_finalize_kernel(const float* __restrict__ ws_sum,
                                     float* __restrict__ out,
                                     float inv_count)
{
    out[0] = 1.0f - ws_sum[0] * inv_count;
}

extern "C" void kernel_launch(void* const* d_in, const int* in_sizes, int n_in,
                              void* d_out, int out_size, void* d_ws, size_t ws_size,
                              hipStream_t stream)
{
    const float* x = (const float*)d_in[0];
    const float* y = (const float*)d_in[1];
    float* out  = (float*)d_out;
    float* wsum = (float*)d_ws;

    const long long total = (long long)in_sizes[0];       // 32*1024*1024
    const int N = (int)(total / ((long long)IMG_H * IMG_W));

    hipMemsetAsync(wsum, 0, sizeof(float), stream);

    dim3 grid(IMG_H / RPB, N);
    ssim_map_sum_kernel<<<grid, TPB, 0, stream>>>(x, y, wsum);

    ssim_finalize_kernel<<<1, 1, 0, stream>>>(wsum, out, 1.0f / (float)total);
}